// Round 9
// baseline (19819.810 us; speedup 1.0000x reference)
//
#include <hip/hip_runtime.h>
#include <math.h>

#define Bx 64
#define Tx 800
#define Ux 80
#define INx 3
#define Hx 400
#define Vx 57
#define Kx 10

// Activation layouts (b fastest):
//  out0/out12 : t*25600 + h*64 + b
//  win        : t*3648  + v*64 + b
//  abk        : t*1920  + j*64 + b
//  xT         : t*192   + d*64 + b
//
// v10 = v9 (fused L1+L2, deadlock-fixed) + async-asm hazard fix.
//  v9 FAILED correctness (absmax 3.7): load_xcat issued an asm volatile
//  sc-load whose result was returned by value while the s_waitcnt vmcnt(0)
//  lived in a LATER separate asm. The compiler (which cannot know an asm
//  load is async) may copy the in-flight destination VGPRs before the wait
//  -> garbage x-plane for L2. Fix: every sc load completes INSIDE its asm
//  block (load + s_waitcnt vmcnt(0) in one asm; paired loads use one block
//  with early-clobber outputs). L1's plain loads are compiler-tracked: safe.
//
// Fusion rationale (v8): per-step cost ~5.3us is work-independent
//  (k_rec<0> == k_rec<15> time despite 2.15x less traffic+math) ->
//  latency-chain bound -> cut superstep COUNT. L1/L2 share weights and have
//  a producer/consumer skew -> run concurrently: 802 supersteps vs 1600.
//  Co-residency: LDS 51.2KB*2=102.4<160KB; 14 waves<=16/CU at VGPR<=128
//  (amdgpu_waves_per_eu(4)); 512 WGs = exactly 2/CU. Even WITHOUT
//  co-residency the dependency is one-way (L2<-L1) -> L1 retires first,
//  L2 runs after: correct either way, just slower.
//  XCD coherence: L2's x-plane reads out12 written THIS dispatch by L1 ->
//  sc0 sc1 LLC-direct loads. L1's x-plane (out0, prior dispatch; L2
//  overwrites only indices <= t-2 after L1 retired its reads) stays plain.
//  L2 waits for L1 flags >= min(t+2, Tx) (clamp: at t=Tx-1 no prefetch
//  is issued; unclamped t+2=801 exceeds L1's max flag 800 -> v8 deadlock).

typedef float v2f __attribute__((ext_vector_type(2)));
typedef float v4f __attribute__((ext_vector_type(4)));

__device__ __forceinline__ float sigf(float x) { return 1.f / (1.f + expf(-x)); }

__device__ __forceinline__ void pk_lo(v2f& acc, v2f w, v2f h) {
    asm("v_pk_fma_f32 %0, %1, %2, %0 op_sel:[0,0,0] op_sel_hi:[0,1,1]"
        : "+v"(acc) : "v"(w), "v"(h));
}
__device__ __forceinline__ void pk_hi(v2f& acc, v2f w, v2f h) {
    asm("v_pk_fma_f32 %0, %1, %2, %0 op_sel:[1,0,0] op_sel_hi:[1,1,1]"
        : "+v"(acc) : "v"(w), "v"(h));
}

// sc-load that COMPLETES inside the asm block (no detached-waitcnt hazard).
__device__ __forceinline__ v4f load1_sc(const float* p) {
    v4f r;
    asm volatile("global_load_dwordx4 %0, %1, off sc0 sc1\n\t"
                 "s_waitcnt vmcnt(0)"
                 : "=v"(r) : "v"(p) : "memory");
    return r;
}
// two concurrent sc-loads, both complete inside the block.
__device__ __forceinline__ void load2_sc(v4f& a, v4f& b,
                                         const float* pa, const float* pb) {
    asm volatile("global_load_dwordx4 %0, %2, off sc0 sc1\n\t"
                 "global_load_dwordx4 %1, %3, off sc0 sc1\n\t"
                 "s_waitcnt vmcnt(0)"
                 : "=&v"(a), "=&v"(b)
                 : "v"(pa), "v"(pb)
                 : "memory");
}

__global__ void k_zero(int* __restrict__ cnt) {
    int i = blockIdx.x * blockDim.x + threadIdx.x;
    if (i < 3 * 16 * 32) cnt[i] = 0;
}

__global__ void k_transpose_x(const float* __restrict__ x, float* __restrict__ xT) {
    int idx = blockIdx.x * blockDim.x + threadIdx.x;
    if (idx >= Tx * INx * Bx) return;
    int b = idx & 63;
    int d = (idx >> 6) % INx;
    int t = idx / (64 * INx);
    xT[idx] = x[((size_t)b * Tx + t) * INx + d];
}

__global__ void k_transpose_oh(const float* __restrict__ oh, float* __restrict__ ohT) {
    int idx = blockIdx.x * blockDim.x + threadIdx.x;
    if (idx >= Ux * Vx * Bx) return;
    int b = idx & 63;
    int uv = idx >> 6;
    int v = uv % Vx;
    int u = uv / Vx;
    ohT[idx] = oh[((size_t)b * Ux + u) * Vx + v];
}

// Wp float2 index: ((us*3*NP) + m)*400 + q ; m = g*NP + p
__global__ void k_packW(const float* __restrict__ Whh, const float* __restrict__ Wih,
                        float* __restrict__ Wp, int NP, int xcols) {
    int idx = blockIdx.x * blockDim.x + threadIdx.x;
    int total = 16 * 3 * NP * 400;
    if (idx >= total) return;
    int q = idx % 400;
    int m = (idx / 400) % (3 * NP);
    int us = idx / (400 * 3 * NP);
    int g = m / NP, p = m % NP;
    int s = q / 25, u = q % 25;
    int row = g * 400 + us * 25 + u;
    float v0, v1;
    if (p < 13) {
        int kl0 = 2 * p, kl1 = 2 * p + 1;
        v0 = (kl0 < 25) ? Whh[(size_t)row * 400 + s * 25 + kl0] : 0.f;
        v1 = (kl1 < 25) ? Whh[(size_t)row * 400 + s * 25 + kl1] : 0.f;
    } else {
        int jx0 = 2 * (p - 13), jx1 = jx0 + 1;
        int kx0 = s * 29 + jx0, kx1 = s * 29 + jx1;
        v0 = (jx0 < 29 && kx0 < xcols) ? Wih[(size_t)row * xcols + kx0] : 0.f;
        v1 = (jx1 < 29 && kx1 < xcols) ? Wih[(size_t)row * xcols + kx1] : 0.f;
    }
    Wp[(size_t)idx * 2]     = v0;
    Wp[(size_t)idx * 2 + 1] = v1;
}

// ---------------- Layer-0 recurrence (unchanged proven structure) ----------------
template <int XP>
__global__ __launch_bounds__(448, 1) void k_rec(
    const float* __restrict__ Wp, const float* __restrict__ prev,
    const float* __restrict__ winb, const float* __restrict__ xT,
    const float* __restrict__ hinit, const float* __restrict__ Wih_small,
    const float* __restrict__ bih, const float* __restrict__ bhh,
    float* __restrict__ outL, int* __restrict__ cnt) {
    constexpr int NP = 13 + XP;
    constexpr int XW = (XP > 0) ? 466 : 4;
    __shared__ __align__(16) float xcat_h[404 * 4];
    __shared__ __align__(16) float xcat_x[2][XW * 4];
    __shared__ __align__(16) float hprev[2][104 * 4];
    __shared__ v2f red2[8 * 400];
    __shared__ float biasLDS[150];
    __shared__ float wih0LDS[225];

    const int tid = threadIdx.x;
    const int us = blockIdx.x & 15;
    const int cg = blockIdx.x >> 4;
    const int cb = cg * 4;
    const int U0 = us * 25;
    const int q = tid;
    const int s = q / 25;
    int* cnt_cg = cnt + cg * 32;

    v2f wr[NP], wz[NP], wn[NP];
    if (q < 400) {
        const v2f* Wp2 = (const v2f*)Wp;
        const size_t base = (size_t)(us * 3 * NP) * 400 + q;
        #pragma unroll
        for (int m = 0; m < NP; ++m) {
            wr[m] = Wp2[base + (size_t)m * 400];
            wz[m] = Wp2[base + (size_t)(NP + m) * 400];
            wn[m] = Wp2[base + (size_t)(2 * NP + m) * 400];
        }
    } else {
        #pragma unroll
        for (int m = 0; m < NP; ++m) {
            wr[m] = (v2f){0.f, 0.f}; wz[m] = (v2f){0.f, 0.f}; wn[m] = (v2f){0.f, 0.f};
        }
    }
    if (tid < 75)        biasLDS[tid] = bih[(tid / 25) * 400 + U0 + (tid % 25)];
    else if (tid < 150)  biasLDS[tid] = bhh[((tid - 75) / 25) * 400 + U0 + ((tid - 75) % 25)];
    if (XP == 0 && tid < 225) {
        int u = tid / 9, r9 = tid % 9, g = r9 / 3, d = r9 % 3;
        wih0LDS[tid] = Wih_small[(size_t)(g * 400 + U0 + u) * 3 + d];
    }
    for (int k = tid; k < 404; k += 448)
        *(v4f*)&xcat_h[k * 4] = (v4f){0.f, 0.f, 0.f, 0.f};
    for (int k = tid; k < 2 * XW; k += 448)
        *(v4f*)&xcat_x[0][k * 4] = (v4f){0.f, 0.f, 0.f, 0.f};

    if (XP == 0) {
        if (tid < 3)
            *(v4f*)&xcat_x[0][tid * 4] = *(const v4f*)(xT + (size_t)tid * 64 + cb);
    }

    for (int t = 0; t < Tx; ++t) {
        const int pl = t & 1;
        if (t > 0) {
            if (tid < 64) {
                int* fp = cnt_cg + (tid & 15);
                int fv = __hip_atomic_load(fp, __ATOMIC_RELAXED, __HIP_MEMORY_SCOPE_AGENT);
                while (!__all(fv >= t)) {
                    __builtin_amdgcn_s_sleep(1);
                    fv = __hip_atomic_load(fp, __ATOMIC_RELAXED, __HIP_MEMORY_SCOPE_AGENT);
                }
            }
            __syncthreads();
        }
        if (tid < 400) {
            v4f hv;
            if (t == 0) {
                hv.x = hinit[(size_t)(cb + 0) * 400 + tid];
                hv.y = hinit[(size_t)(cb + 1) * 400 + tid];
                hv.z = hinit[(size_t)(cb + 2) * 400 + tid];
                hv.w = hinit[(size_t)(cb + 3) * 400 + tid];
            } else {
                hv = load1_sc(outL + (size_t)(t - 1) * 25600 + (size_t)tid * 64 + cb);
            }
            *(v4f*)&xcat_h[tid * 4] = hv;
            int d = tid - U0;
            if ((unsigned)d < 25u) *(v4f*)&hprev[t & 1][d * 4] = hv;
        }
        __syncthreads();   // S1

        if (q < 400) {
            v2f aR0 = {0, 0}, aR1 = {0, 0}, aZ0 = {0, 0}, aZ1 = {0, 0};
            v2f aHN0 = {0, 0}, aHN1 = {0, 0}, aXN0 = {0, 0}, aXN1 = {0, 0};
            const float* hb = &xcat_h[s * 100];
            #pragma unroll
            for (int p = 0; p < 13; ++p) {
                v2f a01 = *(const v2f*)(hb + 8 * p);
                v2f a23 = *(const v2f*)(hb + 8 * p + 2);
                v2f b01 = *(const v2f*)(hb + 8 * p + 4);
                v2f b23 = *(const v2f*)(hb + 8 * p + 6);
                v2f r_ = wr[p], z_ = wz[p], n_ = wn[p];
                pk_lo(aR0, r_, a01);  pk_lo(aR1, r_, a23);
                pk_hi(aR0, r_, b01);  pk_hi(aR1, r_, b23);
                pk_lo(aZ0, z_, a01);  pk_lo(aZ1, z_, a23);
                pk_hi(aZ0, z_, b01);  pk_hi(aZ1, z_, b23);
                pk_lo(aHN0, n_, a01); pk_lo(aHN1, n_, a23);
                pk_hi(aHN0, n_, b01); pk_hi(aHN1, n_, b23);
            }
            red2[0 * 400 + q] = aR0;  red2[1 * 400 + q] = aR1;
            red2[2 * 400 + q] = aZ0;  red2[3 * 400 + q] = aZ1;
            red2[4 * 400 + q] = aHN0; red2[5 * 400 + q] = aHN1;
            red2[6 * 400 + q] = aXN0; red2[7 * 400 + q] = aXN1;
        }
        __syncthreads();   // S2

        if (tid < 64) {
            #pragma unroll
            for (int rep = 0; rep < 2; ++rep) {
                int o = tid + rep * 64;
                if (o < 100) {
                    int u = o >> 2, c = o & 3;
                    int half = c >> 1, e = c & 1;
                    const float* redf = (const float*)red2;
                    float R = 0, Z = 0, HN = 0, XN = 0;
                    #pragma unroll 4
                    for (int s2 = 0; s2 < 16; ++s2) {
                        int idx = s2 * 25 + u;
                        R  += redf[((0 + half) * 400 + idx) * 2 + e];
                        Z  += redf[((2 + half) * 400 + idx) * 2 + e];
                        HN += redf[((4 + half) * 400 + idx) * 2 + e];
                        XN += redf[((6 + half) * 400 + idx) * 2 + e];
                    }
                    R += biasLDS[u] + biasLDS[75 + u];
                    Z += biasLDS[25 + u] + biasLDS[100 + u];
                    XN += biasLDS[50 + u];
                    HN += biasLDS[125 + u];
                    if (XP == 0) {
                        #pragma unroll
                        for (int d = 0; d < 3; ++d) {
                            float xv = xcat_x[pl][d * 4 + c];
                            R  += wih0LDS[u * 9 + 0 + d] * xv;
                            Z  += wih0LDS[u * 9 + 3 + d] * xv;
                            XN += wih0LDS[u * 9 + 6 + d] * xv;
                        }
                    }
                    float r = sigf(R);
                    float z = sigf(Z);
                    float n = tanhf(XN + r * HN);
                    float hp = hprev[t & 1][u * 4 + c];
                    float hnew = (1.f - z) * n + z * hp;
                    __hip_atomic_store(outL + (size_t)t * 25600 + (size_t)(U0 + u) * 64 + cb + c,
                                       hnew, __ATOMIC_RELAXED, __HIP_MEMORY_SCOPE_AGENT);
                }
            }
            asm volatile("s_waitcnt vmcnt(0)" ::: "memory");
            if (tid == 0)
                __hip_atomic_store(cnt_cg + us, t + 1,
                                   __ATOMIC_RELAXED, __HIP_MEMORY_SCOPE_AGENT);
        } else if (t + 1 < Tx) {
            if (XP == 0) {
                if (tid < 67) {
                    int d = tid - 64;
                    *(v4f*)&xcat_x[(t + 1) & 1][d * 4] =
                        *(const v4f*)(xT + (size_t)(t + 1) * 192 + d * 64 + cb);
                }
            }
        }
    }
}

// ---------------- Fused L1+L2 recurrence ----------------
__device__ __forceinline__ const float* xaddr(int kx, int tt, int cb,
    const float* prev, const float* winb, const float* xT) {
    if (kx < 400)      return prev + (size_t)tt * 25600 + (size_t)kx * 64 + cb;
    else if (kx < 457) return winb + (size_t)tt * 3648 + (size_t)(kx - 400) * 64 + cb;
    else               return xT   + (size_t)tt * 192  + (size_t)(kx - 457) * 64 + cb;
}

__global__ __attribute__((amdgpu_flat_work_group_size(448, 448), amdgpu_waves_per_eu(4)))
void k_rec12(
    const float* __restrict__ Wp, float* __restrict__ out0,
    float* __restrict__ out12, const float* __restrict__ winb,
    const float* __restrict__ xT, const float* __restrict__ h1i,
    const float* __restrict__ h2i, const float* __restrict__ bih,
    const float* __restrict__ bhh, int* __restrict__ cnt) {
    constexpr int NP = 28;
    constexpr int XW = 466;
    __shared__ __align__(16) float xcat_h[404 * 4];
    __shared__ __align__(16) float xcat_x[2][XW * 4];
    __shared__ __align__(16) float hprev[2][104 * 4];
    __shared__ v2f red2[8 * 400];
    __shared__ float biasLDS[150];

    const int tid = threadIdx.x;
    const int lay = blockIdx.x >> 8;           // 0 = L1, 1 = L2
    const int blk = blockIdx.x & 255;
    const int us = blk & 15;
    const int cg = blk >> 4;
    const int cb = cg * 4;
    const int U0 = us * 25;
    const int q = tid;
    const int s = q / 25;

    const float* prev  = lay ? out12 : out0;   // x-input stream
    float* outL        = lay ? out0  : out12;  // own output (L2 reuses out0)
    const float* hinit = lay ? h2i   : h1i;
    int* cntOwn = cnt + (lay ? 1024 : 512) + cg * 32;
    int* cntDep = cnt + 512 + cg * 32;         // L1 flags (polled by L2)

    v2f wr[NP], wz[NP], wn[NP];
    if (q < 400) {
        const v2f* Wp2 = (const v2f*)Wp;
        const size_t base = (size_t)(us * 3 * NP) * 400 + q;
        #pragma unroll
        for (int m = 0; m < NP; ++m) {
            wr[m] = Wp2[base + (size_t)m * 400];
            wz[m] = Wp2[base + (size_t)(NP + m) * 400];
            wn[m] = Wp2[base + (size_t)(2 * NP + m) * 400];
        }
    } else {
        #pragma unroll
        for (int m = 0; m < NP; ++m) {
            wr[m] = (v2f){0.f, 0.f}; wz[m] = (v2f){0.f, 0.f}; wn[m] = (v2f){0.f, 0.f};
        }
    }
    if (tid < 75)        biasLDS[tid] = bih[(tid / 25) * 400 + U0 + (tid % 25)];
    else if (tid < 150)  biasLDS[tid] = bhh[((tid - 75) / 25) * 400 + U0 + ((tid - 75) % 25)];
    for (int k = tid; k < 404; k += 448)
        *(v4f*)&xcat_h[k * 4] = (v4f){0.f, 0.f, 0.f, 0.f};
    for (int k = tid; k < 2 * XW; k += 448)
        *(v4f*)&xcat_x[0][k * 4] = (v4f){0.f, 0.f, 0.f, 0.f};

    for (int t = 0; t < Tx; ++t) {
        const int pl = t & 1;
        // ---- wait: own flags >= t; (L2) L1 flags >= min(t+2, Tx)
        if (t > 0 || lay) {
            if (tid < 64) {
                int i16 = tid & 15;
                const bool mine = ((tid >> 4) & 1) == 0;   // lanes 0-15/32-47 own
                int* fp = mine ? (cntOwn + i16) : (cntDep + i16);
                int tdep = t + 2; if (tdep > Tx) tdep = Tx;
                const int tgt = mine ? t : tdep;
                const bool active = mine ? (t > 0) : (lay != 0);
                for (;;) {
                    int fv = active ? __hip_atomic_load(fp, __ATOMIC_RELAXED, __HIP_MEMORY_SCOPE_AGENT)
                                    : 0x7fffffff;
                    if (__all(fv >= tgt)) break;
                    __builtin_amdgcn_s_sleep(1);
                }
            }
            __syncthreads();
        }
        // ---- t==0: stage x(0) into plane 0 (after dep-wait for L2)
        if (t == 0) {
            int kx0 = tid, kx1 = tid + 448;
            const bool hb2 = kx1 < 460;
            if (lay) {
                const float* pa = xaddr(kx0, 0, cb, prev, winb, xT);
                const float* pb = xaddr(hb2 ? kx1 : kx0, 0, cb, prev, winb, xT);
                v4f a, b2;
                load2_sc(a, b2, pa, pb);     // complete inside asm: safe
                *(v4f*)&xcat_x[0][kx0 * 4] = a;
                if (hb2) *(v4f*)&xcat_x[0][kx1 * 4] = b2;
            } else {
                v4f a = *(const v4f*)xaddr(kx0, 0, cb, prev, winb, xT);
                *(v4f*)&xcat_x[0][kx0 * 4] = a;
                if (hb2) {
                    v4f b2 = *(const v4f*)xaddr(kx1, 0, cb, prev, winb, xT);
                    *(v4f*)&xcat_x[0][kx1 * 4] = b2;
                }
            }
        }
        // ---- stage h(t-1)
        if (tid < 400) {
            v4f hv;
            if (t == 0) {
                hv.x = hinit[(size_t)(cb + 0) * 400 + tid];
                hv.y = hinit[(size_t)(cb + 1) * 400 + tid];
                hv.z = hinit[(size_t)(cb + 2) * 400 + tid];
                hv.w = hinit[(size_t)(cb + 3) * 400 + tid];
            } else {
                hv = load1_sc(outL + (size_t)(t - 1) * 25600 + (size_t)tid * 64 + cb);
            }
            *(v4f*)&xcat_h[tid * 4] = hv;
            int d = tid - U0;
            if ((unsigned)d < 25u) *(v4f*)&hprev[t & 1][d * 4] = hv;
        }
        __syncthreads();   // S1: xcat_h + x-plane(pl) ready; red2 free

        // ---- dot
        if (q < 400) {
            v2f aR0 = {0, 0}, aR1 = {0, 0}, aZ0 = {0, 0}, aZ1 = {0, 0};
            v2f aHN0 = {0, 0}, aHN1 = {0, 0}, aXN0 = {0, 0}, aXN1 = {0, 0};
            const float* hb = &xcat_h[s * 100];
            #pragma unroll
            for (int p = 0; p < 13; ++p) {
                v2f a01 = *(const v2f*)(hb + 8 * p);
                v2f a23 = *(const v2f*)(hb + 8 * p + 2);
                v2f b01 = *(const v2f*)(hb + 8 * p + 4);
                v2f b23 = *(const v2f*)(hb + 8 * p + 6);
                v2f r_ = wr[p], z_ = wz[p], n_ = wn[p];
                pk_lo(aR0, r_, a01);  pk_lo(aR1, r_, a23);
                pk_hi(aR0, r_, b01);  pk_hi(aR1, r_, b23);
                pk_lo(aZ0, z_, a01);  pk_lo(aZ1, z_, a23);
                pk_hi(aZ0, z_, b01);  pk_hi(aZ1, z_, b23);
                pk_lo(aHN0, n_, a01); pk_lo(aHN1, n_, a23);
                pk_hi(aHN0, n_, b01); pk_hi(aHN1, n_, b23);
            }
            {
                const float* xb = &xcat_x[pl][s * 29 * 4];
                #pragma unroll
                for (int p = 0; p < 15; ++p) {
                    v2f a01 = *(const v2f*)(xb + 8 * p);
                    v2f a23 = *(const v2f*)(xb + 8 * p + 2);
                    v2f b01 = *(const v2f*)(xb + 8 * p + 4);
                    v2f b23 = *(const v2f*)(xb + 8 * p + 6);
                    v2f r_ = wr[13 + p], z_ = wz[13 + p], n_ = wn[13 + p];
                    pk_lo(aR0, r_, a01);  pk_lo(aR1, r_, a23);
                    pk_hi(aR0, r_, b01);  pk_hi(aR1, r_, b23);
                    pk_lo(aZ0, z_, a01);  pk_lo(aZ1, z_, a23);
                    pk_hi(aZ0, z_, b01);  pk_hi(aZ1, z_, b23);
                    pk_lo(aXN0, n_, a01); pk_lo(aXN1, n_, a23);
                    pk_hi(aXN0, n_, b01); pk_hi(aXN1, n_, b23);
                }
            }
            red2[0 * 400 + q] = aR0;  red2[1 * 400 + q] = aR1;
            red2[2 * 400 + q] = aZ0;  red2[3 * 400 + q] = aZ1;
            red2[4 * 400 + q] = aHN0; red2[5 * 400 + q] = aHN1;
            red2[6 * 400 + q] = aXN0; red2[7 * 400 + q] = aXN1;
        }
        __syncthreads();   // S2

        // ---- wave 0: reduce + activation + sc-store + signal
        if (tid < 64) {
            #pragma unroll
            for (int rep = 0; rep < 2; ++rep) {
                int o = tid + rep * 64;
                if (o < 100) {
                    int u = o >> 2, c = o & 3;
                    int half = c >> 1, e = c & 1;
                    const float* redf = (const float*)red2;
                    float R = 0, Z = 0, HN = 0, XN = 0;
                    #pragma unroll 4
                    for (int s2 = 0; s2 < 16; ++s2) {
                        int idx = s2 * 25 + u;
                        R  += redf[((0 + half) * 400 + idx) * 2 + e];
                        Z  += redf[((2 + half) * 400 + idx) * 2 + e];
                        HN += redf[((4 + half) * 400 + idx) * 2 + e];
                        XN += redf[((6 + half) * 400 + idx) * 2 + e];
                    }
                    R += biasLDS[u] + biasLDS[75 + u];
                    Z += biasLDS[25 + u] + biasLDS[100 + u];
                    XN += biasLDS[50 + u];
                    HN += biasLDS[125 + u];
                    float r = sigf(R);
                    float z = sigf(Z);
                    float n = tanhf(XN + r * HN);
                    float hp = hprev[t & 1][u * 4 + c];
                    float hnew = (1.f - z) * n + z * hp;
                    __hip_atomic_store(outL + (size_t)t * 25600 + (size_t)(U0 + u) * 64 + cb + c,
                                       hnew, __ATOMIC_RELAXED, __HIP_MEMORY_SCOPE_AGENT);
                }
            }
            asm volatile("s_waitcnt vmcnt(0)" ::: "memory");
            if (tid == 0)
                __hip_atomic_store(cntOwn + us, t + 1,
                                   __ATOMIC_RELAXED, __HIP_MEMORY_SCOPE_AGENT);
        } else if (t + 1 < Tx) {
            // ---- waves 1-6: prefetch x(t+1) into other plane
            const int p2 = (t + 1) & 1;
            int kx0 = tid - 64, kx1 = kx0 + 384;
            const bool hb2 = kx1 < 460;
            if (lay) {
                const float* pa = xaddr(kx0, t + 1, cb, prev, winb, xT);
                const float* pb = xaddr(hb2 ? kx1 : kx0, t + 1, cb, prev, winb, xT);
                v4f a, b2;
                load2_sc(a, b2, pa, pb);     // complete inside asm: safe
                *(v4f*)&xcat_x[p2][kx0 * 4] = a;
                if (hb2) *(v4f*)&xcat_x[p2][kx1 * 4] = b2;
            } else {
                v4f a = *(const v4f*)xaddr(kx0, t + 1, cb, prev, winb, xT);
                *(v4f*)&xcat_x[p2][kx0 * 4] = a;
                if (hb2) {
                    v4f b2 = *(const v4f*)xaddr(kx1, t + 1, cb, prev, winb, xT);
                    *(v4f*)&xcat_x[p2][kx1 * 4] = b2;
                }
            }
        }
        // no third __syncthreads: next step's poll-release sync orders LDS.
    }
}

__global__ __launch_bounds__(256) void k_abk(const float* __restrict__ out0,
    const float* __restrict__ Wwin, const float* __restrict__ bwin,
    float* __restrict__ abk) {
    int t = blockIdx.x;
    int b = threadIdx.x & 63;
    int js = threadIdx.x >> 6;
    int j0 = js * 8;
    int nj = min(8, 30 - j0);
    float acc[8];
    for (int i = 0; i < nj; i++) acc[i] = bwin[j0 + i];
    const float* o = out0 + (size_t)t * 25600;
    for (int k = 0; k < Hx; k++) {
        float hv = o[k * 64 + b];
        for (int i = 0; i < nj; i++) acc[i] += Wwin[(j0 + i) * Hx + k] * hv;
    }
    for (int i = 0; i < nj; i++)
        abk[(size_t)t * 1920 + (j0 + i) * 64 + b] = expf(acc[i]);
}

__global__ void k_cumsum(float* __restrict__ abk) {
    int tid = blockIdx.x * blockDim.x + threadIdx.x;
    if (tid >= Kx * Bx) return;
    int b = tid & 63;
    int k = tid >> 6;
    float run = 0.f;
    size_t base = (size_t)(20 + k) * 64 + b;
    for (int t = 0; t < Tx; t++) {
        size_t i = (size_t)t * 1920 + base;
        run += abk[i];
        abk[i] = run;
    }
}

__global__ __launch_bounds__(256) void k_window(const float* __restrict__ abk,
    const float* __restrict__ ohT, float* __restrict__ win) {
    int t = blockIdx.x;
    int b = threadIdx.x & 63;
    int sub = threadIdx.x >> 6;
    __shared__ float phi[Ux][64];

    float al[Kx], be[Kx], kc[Kx];
    const float* ab = abk + (size_t)t * 1920;
    #pragma unroll
    for (int k = 0; k < Kx; k++) {
        al[k] = ab[k * 64 + b];
        be[k] = ab[(10 + k) * 64 + b];
        kc[k] = ab[(20 + k) * 64 + b];
    }
    for (int u = sub * 20; u < sub * 20 + 20; u++) {
        float ssum = 0.f;
        float uf = (float)u;
        #pragma unroll
        for (int k = 0; k < Kx; k++) {
            float d = kc[k] - uf;
            ssum += al[k] * __expf(-be[k] * d * d);
        }
        phi[u][b] = ssum;
    }
    __syncthreads();

    int v0 = sub * 15;
    int nv = min(15, Vx - v0);
    float acc[15];
    for (int i = 0; i < nv; i++) acc[i] = 0.f;
    for (int u = 0; u < Ux; u++) {
        float pv = phi[u][b];
        const float* oh = ohT + (size_t)(u * Vx) * 64;
        for (int i = 0; i < nv; i++) acc[i] += pv * oh[(v0 + i) * 64 + b];
    }
    for (int i = 0; i < nv; i++)
        win[(size_t)t * 3648 + (v0 + i) * 64 + b] = acc[i];
}

__global__ __launch_bounds__(256) void k_mdn(const float* __restrict__ out2,
    const float* __restrict__ Wm, const float* __restrict__ bm,
    float* __restrict__ out) {
    int t = blockIdx.x;
    int b = threadIdx.x & 63;
    int js = threadIdx.x >> 6;
    int j0 = js * 31;
    int nj = min(31, 121 - j0);
    float acc[31];
    for (int i = 0; i < nj; i++) acc[i] = bm[j0 + i];
    const float* o = out2 + (size_t)t * 25600;
    for (int k = 0; k < Hx; k += 4) {
        float i0 = o[k * 64 + b];
        float i1 = o[(k + 1) * 64 + b];
        float i2 = o[(k + 2) * 64 + b];
        float i3 = o[(k + 3) * 64 + b];
        for (int i = 0; i < nj; i++) {
            const float* wp = Wm + (size_t)(j0 + i) * Hx + k;
            float4 qv = *(const float4*)wp;
            acc[i] += qv.x * i0 + qv.y * i1 + qv.z * i2 + qv.w * i3;
        }
    }
    size_t rb = ((size_t)b * Tx + t) * 121;
    for (int i = 0; i < nj; i++) {
        int j = j0 + i;
        float v = acc[i];
        if (j >= 100 && j < 120) v = tanhf(v);
        out[rb + j] = v;
    }
}

extern "C" void kernel_launch(void* const* d_in, const int* in_sizes, int n_in,
                              void* d_out, int out_size, void* d_ws, size_t ws_size,
                              hipStream_t stream) {
    const float* x    = (const float*)d_in[0];
    const float* oneh = (const float*)d_in[1];
    const float* h0i  = (const float*)d_in[2];
    const float* h1i  = (const float*)d_in[3];
    const float* h2i  = (const float*)d_in[4];
    const float* Wih0 = (const float*)d_in[5];
    const float* Whh0 = (const float*)d_in[6];
    const float* bih0 = (const float*)d_in[7];
    const float* bhh0 = (const float*)d_in[8];
    const float* Wih1 = (const float*)d_in[9];
    const float* Whh1 = (const float*)d_in[10];
    const float* bih1 = (const float*)d_in[11];
    const float* bhh1 = (const float*)d_in[12];
    const float* Wwin = (const float*)d_in[13];
    const float* bwin = (const float*)d_in[14];
    const float* Wmdn = (const float*)d_in[15];
    const float* bmdn = (const float*)d_in[16];

    float* ws    = (float*)d_ws;
    float* out0  = ws;                    // 20,480,000
    float* out12 = ws + 20480000;         // 20,480,000
    float* winb  = ws + 40960000;         //  2,918,400
    float* abk   = ws + 43878400;         //  1,536,000
    float* xT    = ws + 45414400;         //    153,600
    float* ohT   = ws + 45568000;         //    291,840
    float* Wp0   = ws + 45859840;         //    499,200
    float* Wp12  = ws + 46359040;         //  1,075,200
    int*   cnt   = (int*)(ws + 47434240); //      1,536 ints

    hipLaunchKernelGGL(k_zero, dim3(6), dim3(256), 0, stream, cnt);
    hipLaunchKernelGGL(k_transpose_x, dim3((Tx * INx * Bx + 255) / 256), dim3(256), 0, stream, x, xT);
    hipLaunchKernelGGL(k_transpose_oh, dim3((Ux * Vx * Bx + 255) / 256), dim3(256), 0, stream, oneh, ohT);
    hipLaunchKernelGGL(k_packW, dim3((16 * 3 * 13 * 400 + 255) / 256), dim3(256), 0, stream,
                       Whh0, Wih0, Wp0, 13, 3);
    hipLaunchKernelGGL(k_packW, dim3((16 * 3 * 28 * 400 + 255) / 256), dim3(256), 0, stream,
                       Whh1, Wih1, Wp12, 28, 460);

    hipLaunchKernelGGL((k_rec<0>), dim3(256), dim3(448), 0, stream,
                       Wp0, (const float*)nullptr, (const float*)nullptr, xT,
                       h0i, Wih0, bih0, bhh0, out0, cnt + 0 * 512);

    hipLaunchKernelGGL(k_abk, dim3(Tx), dim3(256), 0, stream, out0, Wwin, bwin, abk);
    hipLaunchKernelGGL(k_cumsum, dim3(10), dim3(64), 0, stream, abk);
    hipLaunchKernelGGL(k_window, dim3(Tx), dim3(256), 0, stream, abk, ohT, winb);

    // Fused L1+L2: blocks 0-255 = L1 (reads out0, writes out12),
    //              blocks 256-511 = L2 (reads out12 via sc, writes out0).
    hipLaunchKernelGGL(k_rec12, dim3(512), dim3(448), 0, stream,
                       Wp12, out0, out12, winb, xT, h1i, h2i,
                       bih1, bhh1, cnt);

    hipLaunchKernelGGL(k_mdn, dim3(Tx), dim3(256), 0, stream, out0, Wmdn, bmdn, (float*)d_out);
}

// Round 10
// 13246.075 us; speedup vs baseline: 1.4963x; 1.4963x over previous
//
#include <hip/hip_runtime.h>
#include <math.h>

#define Bx 64
#define Tx 800
#define Ux 80
#define INx 3
#define Hx 400
#define Vx 57
#define Kx 10

// Activation layouts (b fastest):
//  out0/out12 : t*25600 + h*64 + b
//  win        : t*3648  + v*64 + b
//  abk        : t*1920  + j*64 + b
//  xT         : t*192   + d*64 + b
//
// v11 = v10 (fused L1+L2, correct) + register-allocation fix.
//  v10 PASSED but k_rec12 had VGPR_Count=64: amdgpu_waves_per_eu(4) (min-
//  only) let the RA target 8 waves/EU -> ~200 live values spilled to
//  scratch; at 2 WG/CU the scratch set (~450KB/CU) thrashes XCD-L2 ->
//  34 GB HBM traffic, 14.7ms. Fix: __launch_bounds__(448,1) — empirically
//  yields VGPR=120 on this body (v5/v6/v7, 3 attribute variants, all 120).
//  At 120: 16 waves/CU max -> 2 WGs (14 waves) co-resident; weights stream
//  from the SHARED cacheable Wp (538KB/XCD, L2-resident), not scratch.
//
// Fusion rationale (v8): per-step cost ~5.3us is work-independent
//  (k_rec<0> == k_rec<15> time despite 2.15x less traffic+math) ->
//  latency-chain bound -> cut superstep COUNT. L1/L2 share weights and
//  have a producer/consumer skew -> run concurrently: ~802 supersteps
//  instead of 1600. Dependency is one-way (L2<-L1): even if co-residency
//  fails, L1 retires then L2 runs -> correct, just serial.
//  XCD coherence: L2's x-plane reads out12 written THIS dispatch by L1 ->
//  sc0 sc1 LLC-direct loads, completed INSIDE one asm block (v10 fix: a
//  detached s_waitcnt lets the compiler copy in-flight dest VGPRs ->
//  garbage). L1's x-plane (out0, prior dispatch) stays plain/cached.
//  L2 waits for L1 flags >= min(t+2, Tx) (v9 fix: unclamped t+2=801
//  exceeds L1's max flag 800 -> deadlock).

typedef float v2f __attribute__((ext_vector_type(2)));
typedef float v4f __attribute__((ext_vector_type(4)));

__device__ __forceinline__ float sigf(float x) { return 1.f / (1.f + expf(-x)); }

__device__ __forceinline__ void pk_lo(v2f& acc, v2f w, v2f h) {
    asm("v_pk_fma_f32 %0, %1, %2, %0 op_sel:[0,0,0] op_sel_hi:[0,1,1]"
        : "+v"(acc) : "v"(w), "v"(h));
}
__device__ __forceinline__ void pk_hi(v2f& acc, v2f w, v2f h) {
    asm("v_pk_fma_f32 %0, %1, %2, %0 op_sel:[1,0,0] op_sel_hi:[1,1,1]"
        : "+v"(acc) : "v"(w), "v"(h));
}

// sc-load that COMPLETES inside the asm block (no detached-waitcnt hazard).
__device__ __forceinline__ v4f load1_sc(const float* p) {
    v4f r;
    asm volatile("global_load_dwordx4 %0, %1, off sc0 sc1\n\t"
                 "s_waitcnt vmcnt(0)"
                 : "=v"(r) : "v"(p) : "memory");
    return r;
}
// two concurrent sc-loads, both complete inside the block.
__device__ __forceinline__ void load2_sc(v4f& a, v4f& b,
                                         const float* pa, const float* pb) {
    asm volatile("global_load_dwordx4 %0, %2, off sc0 sc1\n\t"
                 "global_load_dwordx4 %1, %3, off sc0 sc1\n\t"
                 "s_waitcnt vmcnt(0)"
                 : "=&v"(a), "=&v"(b)
                 : "v"(pa), "v"(pb)
                 : "memory");
}

__global__ void k_zero(int* __restrict__ cnt) {
    int i = blockIdx.x * blockDim.x + threadIdx.x;
    if (i < 3 * 16 * 32) cnt[i] = 0;
}

__global__ void k_transpose_x(const float* __restrict__ x, float* __restrict__ xT) {
    int idx = blockIdx.x * blockDim.x + threadIdx.x;
    if (idx >= Tx * INx * Bx) return;
    int b = idx & 63;
    int d = (idx >> 6) % INx;
    int t = idx / (64 * INx);
    xT[idx] = x[((size_t)b * Tx + t) * INx + d];
}

__global__ void k_transpose_oh(const float* __restrict__ oh, float* __restrict__ ohT) {
    int idx = blockIdx.x * blockDim.x + threadIdx.x;
    if (idx >= Ux * Vx * Bx) return;
    int b = idx & 63;
    int uv = idx >> 6;
    int v = uv % Vx;
    int u = uv / Vx;
    ohT[idx] = oh[((size_t)b * Ux + u) * Vx + v];
}

// Wp float2 index: ((us*3*NP) + m)*400 + q ; m = g*NP + p
__global__ void k_packW(const float* __restrict__ Whh, const float* __restrict__ Wih,
                        float* __restrict__ Wp, int NP, int xcols) {
    int idx = blockIdx.x * blockDim.x + threadIdx.x;
    int total = 16 * 3 * NP * 400;
    if (idx >= total) return;
    int q = idx % 400;
    int m = (idx / 400) % (3 * NP);
    int us = idx / (400 * 3 * NP);
    int g = m / NP, p = m % NP;
    int s = q / 25, u = q % 25;
    int row = g * 400 + us * 25 + u;
    float v0, v1;
    if (p < 13) {
        int kl0 = 2 * p, kl1 = 2 * p + 1;
        v0 = (kl0 < 25) ? Whh[(size_t)row * 400 + s * 25 + kl0] : 0.f;
        v1 = (kl1 < 25) ? Whh[(size_t)row * 400 + s * 25 + kl1] : 0.f;
    } else {
        int jx0 = 2 * (p - 13), jx1 = jx0 + 1;
        int kx0 = s * 29 + jx0, kx1 = s * 29 + jx1;
        v0 = (jx0 < 29 && kx0 < xcols) ? Wih[(size_t)row * xcols + kx0] : 0.f;
        v1 = (jx1 < 29 && kx1 < xcols) ? Wih[(size_t)row * xcols + kx1] : 0.f;
    }
    Wp[(size_t)idx * 2]     = v0;
    Wp[(size_t)idx * 2 + 1] = v1;
}

// ---------------- Layer-0 recurrence (unchanged proven structure) ----------------
template <int XP>
__global__ __launch_bounds__(448, 1) void k_rec(
    const float* __restrict__ Wp, const float* __restrict__ prev,
    const float* __restrict__ winb, const float* __restrict__ xT,
    const float* __restrict__ hinit, const float* __restrict__ Wih_small,
    const float* __restrict__ bih, const float* __restrict__ bhh,
    float* __restrict__ outL, int* __restrict__ cnt) {
    constexpr int NP = 13 + XP;
    constexpr int XW = (XP > 0) ? 466 : 4;
    __shared__ __align__(16) float xcat_h[404 * 4];
    __shared__ __align__(16) float xcat_x[2][XW * 4];
    __shared__ __align__(16) float hprev[2][104 * 4];
    __shared__ v2f red2[8 * 400];
    __shared__ float biasLDS[150];
    __shared__ float wih0LDS[225];

    const int tid = threadIdx.x;
    const int us = blockIdx.x & 15;
    const int cg = blockIdx.x >> 4;
    const int cb = cg * 4;
    const int U0 = us * 25;
    const int q = tid;
    const int s = q / 25;
    int* cnt_cg = cnt + cg * 32;

    v2f wr[NP], wz[NP], wn[NP];
    if (q < 400) {
        const v2f* Wp2 = (const v2f*)Wp;
        const size_t base = (size_t)(us * 3 * NP) * 400 + q;
        #pragma unroll
        for (int m = 0; m < NP; ++m) {
            wr[m] = Wp2[base + (size_t)m * 400];
            wz[m] = Wp2[base + (size_t)(NP + m) * 400];
            wn[m] = Wp2[base + (size_t)(2 * NP + m) * 400];
        }
    } else {
        #pragma unroll
        for (int m = 0; m < NP; ++m) {
            wr[m] = (v2f){0.f, 0.f}; wz[m] = (v2f){0.f, 0.f}; wn[m] = (v2f){0.f, 0.f};
        }
    }
    if (tid < 75)        biasLDS[tid] = bih[(tid / 25) * 400 + U0 + (tid % 25)];
    else if (tid < 150)  biasLDS[tid] = bhh[((tid - 75) / 25) * 400 + U0 + ((tid - 75) % 25)];
    if (XP == 0 && tid < 225) {
        int u = tid / 9, r9 = tid % 9, g = r9 / 3, d = r9 % 3;
        wih0LDS[tid] = Wih_small[(size_t)(g * 400 + U0 + u) * 3 + d];
    }
    for (int k = tid; k < 404; k += 448)
        *(v4f*)&xcat_h[k * 4] = (v4f){0.f, 0.f, 0.f, 0.f};
    for (int k = tid; k < 2 * XW; k += 448)
        *(v4f*)&xcat_x[0][k * 4] = (v4f){0.f, 0.f, 0.f, 0.f};

    if (XP == 0) {
        if (tid < 3)
            *(v4f*)&xcat_x[0][tid * 4] = *(const v4f*)(xT + (size_t)tid * 64 + cb);
    }

    for (int t = 0; t < Tx; ++t) {
        const int pl = t & 1;
        if (t > 0) {
            if (tid < 64) {
                int* fp = cnt_cg + (tid & 15);
                int fv = __hip_atomic_load(fp, __ATOMIC_RELAXED, __HIP_MEMORY_SCOPE_AGENT);
                while (!__all(fv >= t)) {
                    __builtin_amdgcn_s_sleep(1);
                    fv = __hip_atomic_load(fp, __ATOMIC_RELAXED, __HIP_MEMORY_SCOPE_AGENT);
                }
            }
            __syncthreads();
        }
        if (tid < 400) {
            v4f hv;
            if (t == 0) {
                hv.x = hinit[(size_t)(cb + 0) * 400 + tid];
                hv.y = hinit[(size_t)(cb + 1) * 400 + tid];
                hv.z = hinit[(size_t)(cb + 2) * 400 + tid];
                hv.w = hinit[(size_t)(cb + 3) * 400 + tid];
            } else {
                hv = load1_sc(outL + (size_t)(t - 1) * 25600 + (size_t)tid * 64 + cb);
            }
            *(v4f*)&xcat_h[tid * 4] = hv;
            int d = tid - U0;
            if ((unsigned)d < 25u) *(v4f*)&hprev[t & 1][d * 4] = hv;
        }
        __syncthreads();   // S1

        if (q < 400) {
            v2f aR0 = {0, 0}, aR1 = {0, 0}, aZ0 = {0, 0}, aZ1 = {0, 0};
            v2f aHN0 = {0, 0}, aHN1 = {0, 0}, aXN0 = {0, 0}, aXN1 = {0, 0};
            const float* hb = &xcat_h[s * 100];
            #pragma unroll
            for (int p = 0; p < 13; ++p) {
                v2f a01 = *(const v2f*)(hb + 8 * p);
                v2f a23 = *(const v2f*)(hb + 8 * p + 2);
                v2f b01 = *(const v2f*)(hb + 8 * p + 4);
                v2f b23 = *(const v2f*)(hb + 8 * p + 6);
                v2f r_ = wr[p], z_ = wz[p], n_ = wn[p];
                pk_lo(aR0, r_, a01);  pk_lo(aR1, r_, a23);
                pk_hi(aR0, r_, b01);  pk_hi(aR1, r_, b23);
                pk_lo(aZ0, z_, a01);  pk_lo(aZ1, z_, a23);
                pk_hi(aZ0, z_, b01);  pk_hi(aZ1, z_, b23);
                pk_lo(aHN0, n_, a01); pk_lo(aHN1, n_, a23);
                pk_hi(aHN0, n_, b01); pk_hi(aHN1, n_, b23);
            }
            red2[0 * 400 + q] = aR0;  red2[1 * 400 + q] = aR1;
            red2[2 * 400 + q] = aZ0;  red2[3 * 400 + q] = aZ1;
            red2[4 * 400 + q] = aHN0; red2[5 * 400 + q] = aHN1;
            red2[6 * 400 + q] = aXN0; red2[7 * 400 + q] = aXN1;
        }
        __syncthreads();   // S2

        if (tid < 64) {
            #pragma unroll
            for (int rep = 0; rep < 2; ++rep) {
                int o = tid + rep * 64;
                if (o < 100) {
                    int u = o >> 2, c = o & 3;
                    int half = c >> 1, e = c & 1;
                    const float* redf = (const float*)red2;
                    float R = 0, Z = 0, HN = 0, XN = 0;
                    #pragma unroll 4
                    for (int s2 = 0; s2 < 16; ++s2) {
                        int idx = s2 * 25 + u;
                        R  += redf[((0 + half) * 400 + idx) * 2 + e];
                        Z  += redf[((2 + half) * 400 + idx) * 2 + e];
                        HN += redf[((4 + half) * 400 + idx) * 2 + e];
                        XN += redf[((6 + half) * 400 + idx) * 2 + e];
                    }
                    R += biasLDS[u] + biasLDS[75 + u];
                    Z += biasLDS[25 + u] + biasLDS[100 + u];
                    XN += biasLDS[50 + u];
                    HN += biasLDS[125 + u];
                    if (XP == 0) {
                        #pragma unroll
                        for (int d = 0; d < 3; ++d) {
                            float xv = xcat_x[pl][d * 4 + c];
                            R  += wih0LDS[u * 9 + 0 + d] * xv;
                            Z  += wih0LDS[u * 9 + 3 + d] * xv;
                            XN += wih0LDS[u * 9 + 6 + d] * xv;
                        }
                    }
                    float r = sigf(R);
                    float z = sigf(Z);
                    float n = tanhf(XN + r * HN);
                    float hp = hprev[t & 1][u * 4 + c];
                    float hnew = (1.f - z) * n + z * hp;
                    __hip_atomic_store(outL + (size_t)t * 25600 + (size_t)(U0 + u) * 64 + cb + c,
                                       hnew, __ATOMIC_RELAXED, __HIP_MEMORY_SCOPE_AGENT);
                }
            }
            asm volatile("s_waitcnt vmcnt(0)" ::: "memory");
            if (tid == 0)
                __hip_atomic_store(cnt_cg + us, t + 1,
                                   __ATOMIC_RELAXED, __HIP_MEMORY_SCOPE_AGENT);
        } else if (t + 1 < Tx) {
            if (XP == 0) {
                if (tid < 67) {
                    int d = tid - 64;
                    *(v4f*)&xcat_x[(t + 1) & 1][d * 4] =
                        *(const v4f*)(xT + (size_t)(t + 1) * 192 + d * 64 + cb);
                }
            }
        }
    }
}

// ---------------- Fused L1+L2 recurrence ----------------
__device__ __forceinline__ const float* xaddr(int kx, int tt, int cb,
    const float* prev, const float* winb, const float* xT) {
    if (kx < 400)      return prev + (size_t)tt * 25600 + (size_t)kx * 64 + cb;
    else if (kx < 457) return winb + (size_t)tt * 3648 + (size_t)(kx - 400) * 64 + cb;
    else               return xT   + (size_t)tt * 192  + (size_t)(kx - 457) * 64 + cb;
}

__global__ __launch_bounds__(448, 1) void k_rec12(
    const float* __restrict__ Wp, float* __restrict__ out0,
    float* __restrict__ out12, const float* __restrict__ winb,
    const float* __restrict__ xT, const float* __restrict__ h1i,
    const float* __restrict__ h2i, const float* __restrict__ bih,
    const float* __restrict__ bhh, int* __restrict__ cnt) {
    constexpr int NP = 28;
    constexpr int XW = 466;
    __shared__ __align__(16) float xcat_h[404 * 4];
    __shared__ __align__(16) float xcat_x[2][XW * 4];
    __shared__ __align__(16) float hprev[2][104 * 4];
    __shared__ v2f red2[8 * 400];
    __shared__ float biasLDS[150];

    const int tid = threadIdx.x;
    const int lay = blockIdx.x >> 8;           // 0 = L1, 1 = L2
    const int blk = blockIdx.x & 255;
    const int us = blk & 15;
    const int cg = blk >> 4;
    const int cb = cg * 4;
    const int U0 = us * 25;
    const int q = tid;
    const int s = q / 25;

    const float* prev  = lay ? out12 : out0;   // x-input stream
    float* outL        = lay ? out0  : out12;  // own output (L2 reuses out0)
    const float* hinit = lay ? h2i   : h1i;
    int* cntOwn = cnt + (lay ? 1024 : 512) + cg * 32;
    int* cntDep = cnt + 512 + cg * 32;         // L1 flags (polled by L2)

    v2f wr[NP], wz[NP], wn[NP];
    if (q < 400) {
        const v2f* Wp2 = (const v2f*)Wp;
        const size_t base = (size_t)(us * 3 * NP) * 400 + q;
        #pragma unroll
        for (int m = 0; m < NP; ++m) {
            wr[m] = Wp2[base + (size_t)m * 400];
            wz[m] = Wp2[base + (size_t)(NP + m) * 400];
            wn[m] = Wp2[base + (size_t)(2 * NP + m) * 400];
        }
    } else {
        #pragma unroll
        for (int m = 0; m < NP; ++m) {
            wr[m] = (v2f){0.f, 0.f}; wz[m] = (v2f){0.f, 0.f}; wn[m] = (v2f){0.f, 0.f};
        }
    }
    if (tid < 75)        biasLDS[tid] = bih[(tid / 25) * 400 + U0 + (tid % 25)];
    else if (tid < 150)  biasLDS[tid] = bhh[((tid - 75) / 25) * 400 + U0 + ((tid - 75) % 25)];
    for (int k = tid; k < 404; k += 448)
        *(v4f*)&xcat_h[k * 4] = (v4f){0.f, 0.f, 0.f, 0.f};
    for (int k = tid; k < 2 * XW; k += 448)
        *(v4f*)&xcat_x[0][k * 4] = (v4f){0.f, 0.f, 0.f, 0.f};

    for (int t = 0; t < Tx; ++t) {
        const int pl = t & 1;
        // ---- wait: own flags >= t; (L2) L1 flags >= min(t+2, Tx)
        if (t > 0 || lay) {
            if (tid < 64) {
                int i16 = tid & 15;
                const bool mine = ((tid >> 4) & 1) == 0;   // lanes 0-15/32-47 own
                int* fp = mine ? (cntOwn + i16) : (cntDep + i16);
                int tdep = t + 2; if (tdep > Tx) tdep = Tx;
                const int tgt = mine ? t : tdep;
                const bool active = mine ? (t > 0) : (lay != 0);
                for (;;) {
                    int fv = active ? __hip_atomic_load(fp, __ATOMIC_RELAXED, __HIP_MEMORY_SCOPE_AGENT)
                                    : 0x7fffffff;
                    if (__all(fv >= tgt)) break;
                    __builtin_amdgcn_s_sleep(1);
                }
            }
            __syncthreads();
        }
        // ---- t==0: stage x(0) into plane 0 (after dep-wait for L2)
        if (t == 0) {
            int kx0 = tid, kx1 = tid + 448;
            const bool hb2 = kx1 < 460;
            if (lay) {
                const float* pa = xaddr(kx0, 0, cb, prev, winb, xT);
                const float* pb = xaddr(hb2 ? kx1 : kx0, 0, cb, prev, winb, xT);
                v4f a, b2;
                load2_sc(a, b2, pa, pb);     // complete inside asm: safe
                *(v4f*)&xcat_x[0][kx0 * 4] = a;
                if (hb2) *(v4f*)&xcat_x[0][kx1 * 4] = b2;
            } else {
                v4f a = *(const v4f*)xaddr(kx0, 0, cb, prev, winb, xT);
                *(v4f*)&xcat_x[0][kx0 * 4] = a;
                if (hb2) {
                    v4f b2 = *(const v4f*)xaddr(kx1, 0, cb, prev, winb, xT);
                    *(v4f*)&xcat_x[0][kx1 * 4] = b2;
                }
            }
        }
        // ---- stage h(t-1)
        if (tid < 400) {
            v4f hv;
            if (t == 0) {
                hv.x = hinit[(size_t)(cb + 0) * 400 + tid];
                hv.y = hinit[(size_t)(cb + 1) * 400 + tid];
                hv.z = hinit[(size_t)(cb + 2) * 400 + tid];
                hv.w = hinit[(size_t)(cb + 3) * 400 + tid];
            } else {
                hv = load1_sc(outL + (size_t)(t - 1) * 25600 + (size_t)tid * 64 + cb);
            }
            *(v4f*)&xcat_h[tid * 4] = hv;
            int d = tid - U0;
            if ((unsigned)d < 25u) *(v4f*)&hprev[t & 1][d * 4] = hv;
        }
        __syncthreads();   // S1: xcat_h + x-plane(pl) ready; red2 free

        // ---- dot
        if (q < 400) {
            v2f aR0 = {0, 0}, aR1 = {0, 0}, aZ0 = {0, 0}, aZ1 = {0, 0};
            v2f aHN0 = {0, 0}, aHN1 = {0, 0}, aXN0 = {0, 0}, aXN1 = {0, 0};
            const float* hb = &xcat_h[s * 100];
            #pragma unroll
            for (int p = 0; p < 13; ++p) {
                v2f a01 = *(const v2f*)(hb + 8 * p);
                v2f a23 = *(const v2f*)(hb + 8 * p + 2);
                v2f b01 = *(const v2f*)(hb + 8 * p + 4);
                v2f b23 = *(const v2f*)(hb + 8 * p + 6);
                v2f r_ = wr[p], z_ = wz[p], n_ = wn[p];
                pk_lo(aR0, r_, a01);  pk_lo(aR1, r_, a23);
                pk_hi(aR0, r_, b01);  pk_hi(aR1, r_, b23);
                pk_lo(aZ0, z_, a01);  pk_lo(aZ1, z_, a23);
                pk_hi(aZ0, z_, b01);  pk_hi(aZ1, z_, b23);
                pk_lo(aHN0, n_, a01); pk_lo(aHN1, n_, a23);
                pk_hi(aHN0, n_, b01); pk_hi(aHN1, n_, b23);
            }
            {
                const float* xb = &xcat_x[pl][s * 29 * 4];
                #pragma unroll
                for (int p = 0; p < 15; ++p) {
                    v2f a01 = *(const v2f*)(xb + 8 * p);
                    v2f a23 = *(const v2f*)(xb + 8 * p + 2);
                    v2f b01 = *(const v2f*)(xb + 8 * p + 4);
                    v2f b23 = *(const v2f*)(xb + 8 * p + 6);
                    v2f r_ = wr[13 + p], z_ = wz[13 + p], n_ = wn[13 + p];
                    pk_lo(aR0, r_, a01);  pk_lo(aR1, r_, a23);
                    pk_hi(aR0, r_, b01);  pk_hi(aR1, r_, b23);
                    pk_lo(aZ0, z_, a01);  pk_lo(aZ1, z_, a23);
                    pk_hi(aZ0, z_, b01);  pk_hi(aZ1, z_, b23);
                    pk_lo(aXN0, n_, a01); pk_lo(aXN1, n_, a23);
                    pk_hi(aXN0, n_, b01); pk_hi(aXN1, n_, b23);
                }
            }
            red2[0 * 400 + q] = aR0;  red2[1 * 400 + q] = aR1;
            red2[2 * 400 + q] = aZ0;  red2[3 * 400 + q] = aZ1;
            red2[4 * 400 + q] = aHN0; red2[5 * 400 + q] = aHN1;
            red2[6 * 400 + q] = aXN0; red2[7 * 400 + q] = aXN1;
        }
        __syncthreads();   // S2

        // ---- wave 0: reduce + activation + sc-store + signal
        if (tid < 64) {
            #pragma unroll
            for (int rep = 0; rep < 2; ++rep) {
                int o = tid + rep * 64;
                if (o < 100) {
                    int u = o >> 2, c = o & 3;
                    int half = c >> 1, e = c & 1;
                    const float* redf = (const float*)red2;
                    float R = 0, Z = 0, HN = 0, XN = 0;
                    #pragma unroll 4
                    for (int s2 = 0; s2 < 16; ++s2) {
                        int idx = s2 * 25 + u;
                        R  += redf[((0 + half) * 400 + idx) * 2 + e];
                        Z  += redf[((2 + half) * 400 + idx) * 2 + e];
                        HN += redf[((4 + half) * 400 + idx) * 2 + e];
                        XN += redf[((6 + half) * 400 + idx) * 2 + e];
                    }
                    R += biasLDS[u] + biasLDS[75 + u];
                    Z += biasLDS[25 + u] + biasLDS[100 + u];
                    XN += biasLDS[50 + u];
                    HN += biasLDS[125 + u];
                    float r = sigf(R);
                    float z = sigf(Z);
                    float n = tanhf(XN + r * HN);
                    float hp = hprev[t & 1][u * 4 + c];
                    float hnew = (1.f - z) * n + z * hp;
                    __hip_atomic_store(outL + (size_t)t * 25600 + (size_t)(U0 + u) * 64 + cb + c,
                                       hnew, __ATOMIC_RELAXED, __HIP_MEMORY_SCOPE_AGENT);
                }
            }
            asm volatile("s_waitcnt vmcnt(0)" ::: "memory");
            if (tid == 0)
                __hip_atomic_store(cntOwn + us, t + 1,
                                   __ATOMIC_RELAXED, __HIP_MEMORY_SCOPE_AGENT);
        } else if (t + 1 < Tx) {
            // ---- waves 1-6: prefetch x(t+1) into other plane
            const int p2 = (t + 1) & 1;
            int kx0 = tid - 64, kx1 = kx0 + 384;
            const bool hb2 = kx1 < 460;
            if (lay) {
                const float* pa = xaddr(kx0, t + 1, cb, prev, winb, xT);
                const float* pb = xaddr(hb2 ? kx1 : kx0, t + 1, cb, prev, winb, xT);
                v4f a, b2;
                load2_sc(a, b2, pa, pb);     // complete inside asm: safe
                *(v4f*)&xcat_x[p2][kx0 * 4] = a;
                if (hb2) *(v4f*)&xcat_x[p2][kx1 * 4] = b2;
            } else {
                v4f a = *(const v4f*)xaddr(kx0, t + 1, cb, prev, winb, xT);
                *(v4f*)&xcat_x[p2][kx0 * 4] = a;
                if (hb2) {
                    v4f b2 = *(const v4f*)xaddr(kx1, t + 1, cb, prev, winb, xT);
                    *(v4f*)&xcat_x[p2][kx1 * 4] = b2;
                }
            }
        }
        // no third __syncthreads: next step's poll-release sync orders LDS.
    }
}

__global__ __launch_bounds__(256) void k_abk(const float* __restrict__ out0,
    const float* __restrict__ Wwin, const float* __restrict__ bwin,
    float* __restrict__ abk) {
    int t = blockIdx.x;
    int b = threadIdx.x & 63;
    int js = threadIdx.x >> 6;
    int j0 = js * 8;
    int nj = min(8, 30 - j0);
    float acc[8];
    for (int i = 0; i < nj; i++) acc[i] = bwin[j0 + i];
    const float* o = out0 + (size_t)t * 25600;
    for (int k = 0; k < Hx; k++) {
        float hv = o[k * 64 + b];
        for (int i = 0; i < nj; i++) acc[i] += Wwin[(j0 + i) * Hx + k] * hv;
    }
    for (int i = 0; i < nj; i++)
        abk[(size_t)t * 1920 + (j0 + i) * 64 + b] = expf(acc[i]);
}

__global__ void k_cumsum(float* __restrict__ abk) {
    int tid = blockIdx.x * blockDim.x + threadIdx.x;
    if (tid >= Kx * Bx) return;
    int b = tid & 63;
    int k = tid >> 6;
    float run = 0.f;
    size_t base = (size_t)(20 + k) * 64 + b;
    for (int t = 0; t < Tx; t++) {
        size_t i = (size_t)t * 1920 + base;
        run += abk[i];
        abk[i] = run;
    }
}

__global__ __launch_bounds__(256) void k_window(const float* __restrict__ abk,
    const float* __restrict__ ohT, float* __restrict__ win) {
    int t = blockIdx.x;
    int b = threadIdx.x & 63;
    int sub = threadIdx.x >> 6;
    __shared__ float phi[Ux][64];

    float al[Kx], be[Kx], kc[Kx];
    const float* ab = abk + (size_t)t * 1920;
    #pragma unroll
    for (int k = 0; k < Kx; k++) {
        al[k] = ab[k * 64 + b];
        be[k] = ab[(10 + k) * 64 + b];
        kc[k] = ab[(20 + k) * 64 + b];
    }
    for (int u = sub * 20; u < sub * 20 + 20; u++) {
        float ssum = 0.f;
        float uf = (float)u;
        #pragma unroll
        for (int k = 0; k < Kx; k++) {
            float d = kc[k] - uf;
            ssum += al[k] * __expf(-be[k] * d * d);
        }
        phi[u][b] = ssum;
    }
    __syncthreads();

    int v0 = sub * 15;
    int nv = min(15, Vx - v0);
    float acc[15];
    for (int i = 0; i < nv; i++) acc[i] = 0.f;
    for (int u = 0; u < Ux; u++) {
        float pv = phi[u][b];
        const float* oh = ohT + (size_t)(u * Vx) * 64;
        for (int i = 0; i < nv; i++) acc[i] += pv * oh[(v0 + i) * 64 + b];
    }
    for (int i = 0; i < nv; i++)
        win[(size_t)t * 3648 + (v0 + i) * 64 + b] = acc[i];
}

__global__ __launch_bounds__(256) void k_mdn(const float* __restrict__ out2,
    const float* __restrict__ Wm, const float* __restrict__ bm,
    float* __restrict__ out) {
    int t = blockIdx.x;
    int b = threadIdx.x & 63;
    int js = threadIdx.x >> 6;
    int j0 = js * 31;
    int nj = min(31, 121 - j0);
    float acc[31];
    for (int i = 0; i < nj; i++) acc[i] = bm[j0 + i];
    const float* o = out2 + (size_t)t * 25600;
    for (int k = 0; k < Hx; k += 4) {
        float i0 = o[k * 64 + b];
        float i1 = o[(k + 1) * 64 + b];
        float i2 = o[(k + 2) * 64 + b];
        float i3 = o[(k + 3) * 64 + b];
        for (int i = 0; i < nj; i++) {
            const float* wp = Wm + (size_t)(j0 + i) * Hx + k;
            float4 qv = *(const float4*)wp;
            acc[i] += qv.x * i0 + qv.y * i1 + qv.z * i2 + qv.w * i3;
        }
    }
    size_t rb = ((size_t)b * Tx + t) * 121;
    for (int i = 0; i < nj; i++) {
        int j = j0 + i;
        float v = acc[i];
        if (j >= 100 && j < 120) v = tanhf(v);
        out[rb + j] = v;
    }
}

extern "C" void kernel_launch(void* const* d_in, const int* in_sizes, int n_in,
                              void* d_out, int out_size, void* d_ws, size_t ws_size,
                              hipStream_t stream) {
    const float* x    = (const float*)d_in[0];
    const float* oneh = (const float*)d_in[1];
    const float* h0i  = (const float*)d_in[2];
    const float* h1i  = (const float*)d_in[3];
    const float* h2i  = (const float*)d_in[4];
    const float* Wih0 = (const float*)d_in[5];
    const float* Whh0 = (const float*)d_in[6];
    const float* bih0 = (const float*)d_in[7];
    const float* bhh0 = (const float*)d_in[8];
    const float* Wih1 = (const float*)d_in[9];
    const float* Whh1 = (const float*)d_in[10];
    const float* bih1 = (const float*)d_in[11];
    const float* bhh1 = (const float*)d_in[12];
    const float* Wwin = (const float*)d_in[13];
    const float* bwin = (const float*)d_in[14];
    const float* Wmdn = (const float*)d_in[15];
    const float* bmdn = (const float*)d_in[16];

    float* ws    = (float*)d_ws;
    float* out0  = ws;                    // 20,480,000
    float* out12 = ws + 20480000;         // 20,480,000
    float* winb  = ws + 40960000;         //  2,918,400
    float* abk   = ws + 43878400;         //  1,536,000
    float* xT    = ws + 45414400;         //    153,600
    float* ohT   = ws + 45568000;         //    291,840
    float* Wp0   = ws + 45859840;         //    499,200
    float* Wp12  = ws + 46359040;         //  1,075,200
    int*   cnt   = (int*)(ws + 47434240); //      1,536 ints

    hipLaunchKernelGGL(k_zero, dim3(6), dim3(256), 0, stream, cnt);
    hipLaunchKernelGGL(k_transpose_x, dim3((Tx * INx * Bx + 255) / 256), dim3(256), 0, stream, x, xT);
    hipLaunchKernelGGL(k_transpose_oh, dim3((Ux * Vx * Bx + 255) / 256), dim3(256), 0, stream, oneh, ohT);
    hipLaunchKernelGGL(k_packW, dim3((16 * 3 * 13 * 400 + 255) / 256), dim3(256), 0, stream,
                       Whh0, Wih0, Wp0, 13, 3);
    hipLaunchKernelGGL(k_packW, dim3((16 * 3 * 28 * 400 + 255) / 256), dim3(256), 0, stream,
                       Whh1, Wih1, Wp12, 28, 460);

    hipLaunchKernelGGL((k_rec<0>), dim3(256), dim3(448), 0, stream,
                       Wp0, (const float*)nullptr, (const float*)nullptr, xT,
                       h0i, Wih0, bih0, bhh0, out0, cnt + 0 * 512);

    hipLaunchKernelGGL(k_abk, dim3(Tx), dim3(256), 0, stream, out0, Wwin, bwin, abk);
    hipLaunchKernelGGL(k_cumsum, dim3(10), dim3(64), 0, stream, abk);
    hipLaunchKernelGGL(k_window, dim3(Tx), dim3(256), 0, stream, abk, ohT, winb);

    // Fused L1+L2: blocks 0-255 = L1 (reads out0, writes out12),
    //              blocks 256-511 = L2 (reads out12 via sc, writes out0).
    hipLaunchKernelGGL(k_rec12, dim3(512), dim3(448), 0, stream,
                       Wp12, out0, out12, winb, xT, h1i, h2i,
                       bih1, bhh1, cnt);

    hipLaunchKernelGGL(k_mdn, dim3(Tx), dim3(256), 0, stream, out0, Wmdn, bmdn, (float*)d_out);
}